// Round 12
// baseline (536.439 us; speedup 1.0000x reference)
//
#include <hip/hip_runtime.h>
#include <cstdint>
#include <cstddef>

#define B_ 8
#define C_ 64
#define N_ 4096
#define O_ 64
#define ROWS_ (B_*N_)          // 32768
#define NSPLIT_ 2              // candidate splits per row in k_knn
#define CAPB_ 33               // per-lane LDS candidate cap (odd u64 stride: 2-way, free)
#define TAU_TILES_ 8           // tiles scanned for the tau upper bound
#define MIDROWS_ 16            // rows per k_mid block (TLP: 2048 blocks)

typedef unsigned long long u64;
typedef unsigned int u32;
typedef unsigned short u16;
typedef __attribute__((ext_vector_type(8))) short bf16x8;   // 8 bf16 = 4 VGPR
typedef __attribute__((ext_vector_type(16))) float f32x16;  // MFMA 32x32 acc

#define MFMA32(A,Bv,Cv) __builtin_amdgcn_mfma_f32_32x32x16_bf16(A,Bv,Cv,0,0,0)

// ---- workspace layout (bytes), total 35,782,656 ----
// xf   [ROWS][64] f32 : 0           (8 MB)   alive: transpose -> mid
// sq   [ROWS]     f32 : 8388608     (128 KB) alive: transpose -> knn
// kd   [ROWS][2][16] u32 : 8519680  (4 MB)   alive: knn -> mid
// ki   [ROWS][2][16] u16 : 16908288 (2 MB)   alive: knn -> mid
// pack [B][128][12][64][8] bf16 : 21102592 (12 MB) alive: transpose -> knn
// -- aliases (dead regions reused): --
// h1   [ROWS][64] f32 : 21102592 (over pack head, dead after knn; mid -> final)
// bn   acc[128]       : 33685504 (own region; zeroed by k_knn block 0)
#define OFF_XF   0
#define OFF_SQ   8388608
#define OFF_KD   8519680
#define OFF_KI   16908288
#define OFF_PACK 21102592
#define OFF_H1   21102592
#define OFF_BN   33685504

__device__ __forceinline__ void insert16(u64 kv[16], u64 key) {
  if (key < kv[15]) {
#pragma unroll
    for (int j = 15; j > 0; --j) {
      u64 a = kv[j-1], b = kv[j];
      kv[j] = (key < a) ? a : ((key < b) ? key : b);
    }
    kv[0] = (key < kv[0]) ? key : kv[0];
  }
}

// ---------------- K1: transpose [B,C,N] -> xf[B,N,C], sq, and bf16 split-pack ----
__global__ __launch_bounds__(256) void k_transpose(const float* __restrict__ x,
                                                   float* __restrict__ xf,
                                                   float* __restrict__ sq,
                                                   u16* __restrict__ pack) {
  __shared__ float lds[64 * 65];
  const int b  = blockIdx.x >> 6;          // 8 batches
  const int n0 = (blockIdx.x & 63) << 6;   // 64 n-tiles of 64
  const int tid = threadIdx.x;
  const float* xb = x + (size_t)b * C_ * N_;
  {
    const int nn = tid & 63;
    const int c0 = tid >> 6;
#pragma unroll
    for (int i = 0; i < 16; ++i) {
      int c = c0 + i * 4;
      lds[c * 65 + nn] = xb[(size_t)c * N_ + n0 + nn];   // coalesced over n
    }
  }
  __syncthreads();
  {
    const int cc  = tid & 63;
    const int nn0 = tid >> 6;
#pragma unroll
    for (int i = 0; i < 16; ++i) {
      int nn = nn0 + i * 4;
      xf[((size_t)(b * N_ + n0 + nn)) * 64 + cc] = lds[cc * 65 + nn]; // coalesced over c
    }
  }
  if (tid < 64) {
    float s = 0.f;
#pragma unroll
    for (int c = 0; c < 64; ++c) { float v = lds[c * 65 + tid]; s += v * v; }
    sq[b * N_ + n0 + tid] = s;
  }
  {
    const int lane = tid & 63;
    const int slice = tid >> 6;                  // 4 k-slices of 16
    const int kb = slice * 16 + (lane >> 5) * 8;
#pragma unroll
    for (int tl = 0; tl < 2; ++tl) {
      const int nl = tl * 32 + (lane & 31);
      bf16x8 H, M, L;
#pragma unroll
      for (int j = 0; j < 8; ++j) {
        float f = lds[(kb + j) * 65 + nl];
        u32 u = __float_as_uint(f);
        u32 rh = (u + 0x7FFFu + ((u >> 16) & 1u)) >> 16;   // RNE to bf16
        float bh = __uint_as_float(rh << 16);
        float f1 = f - bh;                                  // exact (Sterbenz)
        u = __float_as_uint(f1);
        u32 rm = (u + 0x7FFFu + ((u >> 16) & 1u)) >> 16;
        float bm = __uint_as_float(rm << 16);
        float f2 = f1 - bm;                                 // exact
        u = __float_as_uint(f2);
        u32 rl = (u + 0x7FFFu + ((u >> 16) & 1u)) >> 16;
        H[j] = (short)rh; M[j] = (short)rm; L[j] = (short)rl;
      }
      const int tile = ((blockIdx.x & 63) << 1) + tl;
      u16* basep = pack + ((size_t)(b * 128 + tile) * 12) * 512 + lane * 8;
      *(bf16x8*)(basep + (size_t)(0 + slice) * 512) = H;
      *(bf16x8*)(basep + (size_t)(4 + slice) * 512) = M;
      *(bf16x8*)(basep + (size_t)(8 + slice) * 512) = L;
    }
  }
}

// ---------------- K2: producer/consumer MFMA distances + tau-bound top-16 ----------
// grid: 1024 blocks = 8 b x 64 qpair x 2 split; block = 4 waves = 2 (prod,cons) pairs.
// Pair p handles query tile qt = qp*2+p. Producer wave: fragments + 24 MFMA + write
// 16 dists/lane to LDS dbuf slot s&1. Consumer wave: read slot (s-1)&1, run selection
// (tau-scan tiles 0..7, then collect 0..63) -- concurrent on separate pipes.
// One __syncthreads per step flips the double buffer (2 slots => race-free).
// Producer parity alternates with blockIdx for SIMD pipe mixing.
// Numerics: producer writes acc0[r]+acc1[r]; consumer d = fmaf(-2,d,sq): bit-identical
// to previous rounds. C/D layout: col=lane&31, row=(reg&3)+8*(reg>>2)+4*(lane>>5).
#define KNN_LOAD(P, mt) do { const u16* ap_ = pb + (size_t)(mt) * (12*512); \
  P##h0 = *(const bf16x8*)(ap_ + 0*512);  P##h1 = *(const bf16x8*)(ap_ + 1*512); \
  P##h2 = *(const bf16x8*)(ap_ + 2*512);  P##h3 = *(const bf16x8*)(ap_ + 3*512); \
  P##m0 = *(const bf16x8*)(ap_ + 4*512);  P##m1 = *(const bf16x8*)(ap_ + 5*512); \
  P##m2 = *(const bf16x8*)(ap_ + 6*512);  P##m3 = *(const bf16x8*)(ap_ + 7*512); \
  P##l0 = *(const bf16x8*)(ap_ + 8*512);  P##l1 = *(const bf16x8*)(ap_ + 9*512); \
  P##l2 = *(const bf16x8*)(ap_ +10*512);  P##l3 = *(const bf16x8*)(ap_ +11*512); } while(0)

#define KNN_MFMA(P) \
  acc0 = MFMA32(P##h0, ql0, acc0);  acc1 = MFMA32(P##h1, ql1, acc1); \
  acc0 = MFMA32(P##l0, qh0, acc0);  acc1 = MFMA32(P##l1, qh1, acc1); \
  acc0 = MFMA32(P##m0, qm0, acc0);  acc1 = MFMA32(P##m1, qm1, acc1); \
  acc0 = MFMA32(P##h0, qm0, acc0);  acc1 = MFMA32(P##h1, qm1, acc1); \
  acc0 = MFMA32(P##m0, qh0, acc0);  acc1 = MFMA32(P##m1, qh1, acc1); \
  acc0 = MFMA32(P##h0, qh0, acc0);  acc1 = MFMA32(P##h1, qh1, acc1); \
  acc0 = MFMA32(P##h2, ql2, acc0);  acc1 = MFMA32(P##h3, ql3, acc1); \
  acc0 = MFMA32(P##l2, qh2, acc0);  acc1 = MFMA32(P##l3, qh3, acc1); \
  acc0 = MFMA32(P##m2, qm2, acc0);  acc1 = MFMA32(P##m3, qm3, acc1); \
  acc0 = MFMA32(P##h2, qm2, acc0);  acc1 = MFMA32(P##h3, qm3, acc1); \
  acc0 = MFMA32(P##m2, qh2, acc0);  acc1 = MFMA32(P##m3, qh3, acc1); \
  acc0 = MFMA32(P##h2, qh2, acc0);  acc1 = MFMA32(P##h3, qh3, acc1);

#define SQ_LOADN(MT) do { const float* sp_ = sqb + (MT) * 32 + 4 * h; \
  svn0 = *(const float4*)(sp_);      svn1 = *(const float4*)(sp_ + 8); \
  svn2 = *(const float4*)(sp_ + 16); svn3 = *(const float4*)(sp_ + 24); } while(0)

// tau-scan select: direct sorted insert-8 (u32 dist-only keys); d from LDS dist tile
#define SEL_T8() do { \
  float sqv_[16] = {svc0.x, svc0.y, svc0.z, svc0.w, svc1.x, svc1.y, svc1.z, svc1.w, \
                    svc2.x, svc2.y, svc2.z, svc2.w, svc3.x, svc3.y, svc3.z, svc3.w}; \
  float dd_[16]  = {dv0.x, dv0.y, dv0.z, dv0.w, dv1.x, dv1.y, dv1.z, dv1.w, \
                    dv2.x, dv2.y, dv2.z, dv2.w, dv3.x, dv3.y, dv3.z, dv3.w}; \
_Pragma("unroll") \
  for (int r_ = 0; r_ < 16; ++r_) { \
    float d_ = fmaf(-2.f, dd_[r_], sqv_[r_]); \
    u32 u_ = __float_as_uint(d_); \
    u_ ^= ((int)u_ < 0) ? 0xFFFFFFFFu : 0x80000000u; \
    if (u_ < kv1[7]) { \
_Pragma("unroll") \
      for (int j_ = 7; j_ > 0; --j_) { \
        u32 a_ = kv1[j_-1], b_ = kv1[j_]; \
        kv1[j_] = (u_ < a_) ? a_ : ((u_ < b_) ? u_ : b_); \
      } \
      kv1[0] = (u_ < kv1[0]) ? u_ : kv1[0]; \
    } \
  } \
} while(0)

// collect select: filtered LDS push + one batched drain vote per tile
#define SEL_C(MT) do { \
  const u32 ic_ = (u32)((MT) * 32 + 4 * h); \
  float sqv_[16] = {svc0.x, svc0.y, svc0.z, svc0.w, svc1.x, svc1.y, svc1.z, svc1.w, \
                    svc2.x, svc2.y, svc2.z, svc2.w, svc3.x, svc3.y, svc3.z, svc3.w}; \
  float dd_[16]  = {dv0.x, dv0.y, dv0.z, dv0.w, dv1.x, dv1.y, dv1.z, dv1.w, \
                    dv2.x, dv2.y, dv2.z, dv2.w, dv3.x, dv3.y, dv3.z, dv3.w}; \
_Pragma("unroll") \
  for (int r_ = 0; r_ < 16; ++r_) { \
    float d_ = fmaf(-2.f, dd_[r_], sqv_[r_]); \
    u32 u_ = __float_as_uint(d_); \
    u_ ^= ((int)u_ < 0) ? 0xFFFFFFFFu : 0x80000000u; \
    if (u_ <= tauk) { \
      myc[cnt] = ((u64)u_ << 32) | (u64)(ic_ + (u32)((r_ & 3) + 8 * (r_ >> 2))); \
      ++cnt; \
    } \
  } \
  if (__any(cnt >= CAPB_ - 16)) {            /* capacity: <=16 adds/tile, cap 33 */ \
    for (int i_ = 0; i_ < cnt; ++i_) insert16(kv, myc[i_]); \
    cnt = 0; \
  } \
} while(0)

__global__ __launch_bounds__(256, 2) void k_knn(const u16* __restrict__ pack,
                                                const float* __restrict__ sq,
                                                u32* __restrict__ kd,
                                                u16* __restrict__ ki,
                                                float* __restrict__ bn_acc) {
  __shared__ float dist[2 * 2 * 64 * 16];    // [pair][slot][lane][16] = 16 KB
  __shared__ u64 cand[128 * CAPB_];          // consumer lanes only: 33.8 KB
  const int bx = blockIdx.x;
  const int tid = threadIdx.x;
  if (bx == 0 && tid < 128) bn_acc[tid] = 0.f;   // OFF_BN region untouched elsewhere
  const int split = bx & 1;
  const int qp = (bx >> 1) & 63;
  const int b = bx >> 7;
  const int lane = tid & 63;
  const int wid = tid >> 6;
  const int pair = wid >> 1;                 // 2 pairs per block
  const bool prod = ((wid ^ bx) & 1) == 0;   // parity-mixed across SIMDs
  const int qt = qp * 2 + pair;              // query tile 0..127
  const int h = lane >> 5;
  const u16* pb = pack + (size_t)b * (128 * 12 * 512) + lane * 8;
  const float* sqb = sq + b * N_;
  const int mbase = split * 64;

  // ---- producer state: persistent query fragments (only producer loads them) ----
  bf16x8 qh0, qh1, qh2, qh3, qm0, qm1, qm2, qm3, ql0, ql1, ql2, ql3;
  if (prod) {
    const u16* qp_ = pb + (size_t)qt * (12 * 512);
    qh0 = *(const bf16x8*)(qp_ + 0*512);  qh1 = *(const bf16x8*)(qp_ + 1*512);
    qh2 = *(const bf16x8*)(qp_ + 2*512);  qh3 = *(const bf16x8*)(qp_ + 3*512);
    qm0 = *(const bf16x8*)(qp_ + 4*512);  qm1 = *(const bf16x8*)(qp_ + 5*512);
    qm2 = *(const bf16x8*)(qp_ + 6*512);  qm3 = *(const bf16x8*)(qp_ + 7*512);
    ql0 = *(const bf16x8*)(qp_ + 8*512);  ql1 = *(const bf16x8*)(qp_ + 9*512);
    ql2 = *(const bf16x8*)(qp_ + 10*512); ql3 = *(const bf16x8*)(qp_ + 11*512);
  }
  bf16x8 Ah0, Ah1, Ah2, Ah3, Am0, Am1, Am2, Am3, Al0, Al1, Al2, Al3;

  // ---- consumer state ----
  u32 kv1[8];
  u64 kv[16];
  u32 tauk = 0;
  int cnt = 0;
  u64* myc = cand + (size_t)(pair * 64 + lane) * CAPB_;
  float4 svc0, svc1, svc2, svc3, svn0, svn1, svn2, svn3;
  float4 dv0, dv1, dv2, dv3;
  if (!prod) {
#pragma unroll
    for (int j = 0; j < 8; ++j) kv1[j] = 0xFF800000u;  // flip(+INF) sentinel
    const float* sp_ = sqb + mbase * 32 + 4 * h;       // sq for first consumed tile
    svc0 = *(const float4*)(sp_);      svc1 = *(const float4*)(sp_ + 8);
    svc2 = *(const float4*)(sp_ + 16); svc3 = *(const float4*)(sp_ + 24);
  }

  // ---- unified pipeline: 72 produce steps, consumer lags by 1, +1 drain step ----
#pragma unroll 1
  for (int s = 0; s < 73; ++s) {
    if (prod) {
      if (s < 72) {
        const int mt = mbase + (s < TAU_TILES_ ? s : s - TAU_TILES_);
        KNN_LOAD(A, mt);
        f32x16 acc0 = {0,0,0,0,0,0,0,0,0,0,0,0,0,0,0,0};
        f32x16 acc1 = {0,0,0,0,0,0,0,0,0,0,0,0,0,0,0,0};
        KNN_MFMA(A)
        float* wp = dist + ((size_t)(pair * 2 + (s & 1)) * 64 + lane) * 16;
        float4 w;
        w.x = acc0[0]  + acc1[0];  w.y = acc0[1]  + acc1[1];
        w.z = acc0[2]  + acc1[2];  w.w = acc0[3]  + acc1[3];
        *(float4*)(wp) = w;
        w.x = acc0[4]  + acc1[4];  w.y = acc0[5]  + acc1[5];
        w.z = acc0[6]  + acc1[6];  w.w = acc0[7]  + acc1[7];
        *(float4*)(wp + 4) = w;
        w.x = acc0[8]  + acc1[8];  w.y = acc0[9]  + acc1[9];
        w.z = acc0[10] + acc1[10]; w.w = acc0[11] + acc1[11];
        *(float4*)(wp + 8) = w;
        w.x = acc0[12] + acc1[12]; w.y = acc0[13] + acc1[13];
        w.z = acc0[14] + acc1[14]; w.w = acc0[15] + acc1[15];
        *(float4*)(wp + 12) = w;
      }
    } else {
      if (s >= 1) {
        const int t = s - 1;
        const int mt = mbase + (t < TAU_TILES_ ? t : t - TAU_TILES_);
        const int tn = t + 1;
        const int mtn = mbase + (tn < TAU_TILES_ ? tn : ((tn - TAU_TILES_) & 63));
        SQ_LOADN(mtn);                       // prefetch next tile's sq
        const float* dpd = dist + ((size_t)(pair * 2 + ((s - 1) & 1)) * 64 + lane) * 16;
        dv0 = *(const float4*)(dpd);
        dv1 = *(const float4*)(dpd + 4);
        dv2 = *(const float4*)(dpd + 8);
        dv3 = *(const float4*)(dpd + 12);
        if (t < TAU_TILES_) {
          SEL_T8();
        } else {
          if (t == TAU_TILES_) {             // tau from completed tau-scan
            u32 tk = kv1[7];
            u32 pk = (u32)__shfl_xor((int)tk, 32);
            tauk = (tk > pk) ? tk : pk;      // >= exact 16th-smallest of split
#pragma unroll
            for (int j = 0; j < 16; ++j) kv[j] = 0xFF8000000000FFFFull;
            cnt = 0;
          }
          SEL_C(mt);
        }
        svc0 = svn0; svc1 = svn1; svc2 = svn2; svc3 = svn3;
      }
    }
    __syncthreads();                         // flip double buffer (uniform)
  }

  if (!prod) {
    for (int i = 0; i < cnt; ++i) insert16(kv, myc[i]);  // final drain

    // merge lane halves (half-cleaner -> bitonic), then bitonic-merge sort
    u64 m[16];
#pragma unroll
    for (int j = 0; j < 16; ++j) {
      u64 p = __shfl_xor(kv[15 - j], 32);
      m[j] = (kv[j] < p) ? kv[j] : p;
    }
#pragma unroll
    for (int d = 8; d >= 1; d >>= 1) {
#pragma unroll
      for (int j = 0; j < 16; ++j) {
        if ((j & d) == 0) {
          u64 a = m[j], c = m[j | d];
          m[j] = (a < c) ? a : c;
          m[j | d] = (a < c) ? c : a;
        }
      }
    }

    if (lane < 32) {
      const int row = b * N_ + qt * 32 + lane;
      u32* dp = kd + ((size_t)row * NSPLIT_ + split) * 16;
      u16* ip = ki + ((size_t)row * NSPLIT_ + split) * 16;
#pragma unroll
      for (int j = 0; j < 16; ++j) {
        dp[j] = (u32)(m[j] >> 32);
        ip[j] = (u16)(m[j] & 0xFFFFu);
      }
    }
  }
}

// ---------------- K3: fused merge + GIN aggregation + GEMM1 + BN partial sums ----
__global__ __launch_bounds__(256) void k_mid(const u32* __restrict__ kd,
                                             const u16* __restrict__ ki,
                                             const float* __restrict__ xf,
                                             const float* __restrict__ eps_gin,
                                             const float* __restrict__ w1,
                                             const float* __restrict__ b1,
                                             float* __restrict__ h1,
                                             float* __restrict__ bn_acc) {
  __shared__ float wT[64 * 65];                 // w1 transposed: wT[o][c] (16.6 KB)
  __shared__ float hL[MIDROWS_ * 65];           // aggregated rows (4.2 KB)
  __shared__ int   knnL[MIDROWS_ * 16];
  __shared__ float rs[4][64], rs2[4][64];
  const int tid = threadIdx.x;
  const int r0 = blockIdx.x * MIDROWS_;
#pragma unroll
  for (int i = 0; i < 16; ++i) {
    int idx = tid + i * 256;                    // w1[c][o], idx = c*64+o
    wT[(idx & 63) * 65 + (idx >> 6)] = w1[idx];
  }
  {
    const int row = tid >> 4;                   // 16 rows x 16 j = 256 threads
    const int j = tid & 15;
    const u32* dp = kd + (size_t)(r0 + row) * (NSPLIT_ * 16);
    const u16* ip = ki + (size_t)(r0 + row) * (NSPLIT_ * 16);
    u64 a = ((u64)dp[j] << 32) | ip[j];
    u64 bb = ((u64)dp[16 + (15 - j)] << 32) | ip[16 + (15 - j)];
    knnL[row * 16 + j] = (int)((a < bb ? a : bb) & 0xFFFFu);  // set semantics
  }
  __syncthreads();
  const int c = tid & 63;
  const int q = tid >> 6;
  const int b = r0 >> 12;
  const float* xfb = xf + (size_t)b * N_ * 64;
  const float eps1 = 1.f + eps_gin[0];
#pragma unroll
  for (int i = 0; i < 4; ++i) {
    int rl = q * 4 + i;                         // wave-uniform row
    float v = eps1 * xfb[(size_t)((r0 & (N_ - 1)) + rl) * 64 + c];
    const int* kn = knnL + rl * 16;
#pragma unroll
    for (int j = 0; j < 16; ++j) {
      int mr = kn[j];                           // wave-uniform LDS broadcast
      v += xfb[(size_t)mr * 64 + c];            // coalesced 256B row read
    }
    hL[rl * 65 + c] = v;
  }
  __syncthreads();
  const int o = c;
  const float bias = b1[o];
  float s = 0.f, s2 = 0.f;
#pragma unroll
  for (int i = 0; i < 4; ++i) {
    int rl = q * 4 + i;
    float acc = bias;
#pragma unroll
    for (int k = 0; k < 16; ++k) {
      float4 hv = *(const float4*)&hL[rl * 65 + 4 * k];   // uniform -> broadcast
      float4 wv = *(const float4*)&wT[o * 65 + 4 * k];    // pad-65: conflict-free
      acc += hv.x * wv.x; acc += hv.y * wv.y;             // ascending c: same order
      acc += hv.z * wv.z; acc += hv.w * wv.w;             //  as previous kernel
    }
    h1[(size_t)(r0 + rl) * 64 + o] = acc;
    s += acc; s2 += acc * acc;
  }
  rs[q][o] = s; rs2[q][o] = s2;
  __syncthreads();
  if (tid < 64) {
    float ts  = rs[0][tid] + rs[1][tid] + rs[2][tid] + rs[3][tid];
    float ts2 = rs2[0][tid] + rs2[1][tid] + rs2[2][tid] + rs2[3][tid];
    atomicAdd(&bn_acc[tid], ts);
    atomicAdd(&bn_acc[64 + tid], ts2);
  }
}

// ---------------- K4: BN finalize + apply + GELU(erf) + GEMM2 + transposed store ----
__global__ __launch_bounds__(256) void k_final(const float* __restrict__ h1,
                                               const float* __restrict__ bn_acc,
                                               const float* __restrict__ gamma,
                                               const float* __restrict__ beta,
                                               const float* __restrict__ w2,
                                               const float* __restrict__ b2,
                                               float* __restrict__ out) {
  __shared__ float wT2[64 * 65];                // w2 transposed: wT2[o2][oo]
  __shared__ float hg[64 * 65];                 // padded: kills stride-64 conflicts
  __shared__ float scsh[128];
  const int tid = threadIdx.x;
#pragma unroll
  for (int i = 0; i < 16; ++i) {
    int idx = tid + i * 256;                    // w2[oo][o2], idx = oo*64+o2
    wT2[(idx & 63) * 65 + (idx >> 6)] = w2[idx];
  }
  if (tid < 64) {                               // fused BN finalize
    const float inv = 1.f / (float)ROWS_;
    float mean = bn_acc[tid] * inv;
    float var  = bn_acc[64 + tid] * inv - mean * mean;
    float sc = gamma[tid] * rsqrtf(var + 1e-5f);
    scsh[tid] = sc;
    scsh[64 + tid] = beta[tid] - mean * sc;
  }
  __syncthreads();
  const int r0 = blockIdx.x * 64;
  const int b  = r0 >> 12;
  const int n0 = r0 & (N_ - 1);
  const int o = tid & 63;
  const int q = tid >> 6;
  const float sc = scsh[o], sh = scsh[64 + o];
#pragma unroll
  for (int i = 0; i < 16; ++i) {
    int rl = q + i * 4;
    float v = h1[(size_t)(r0 + rl) * 64 + o] * sc + sh;
    float g = 0.5f * v * (1.f + erff(v * 0.70710678118654752f));
    hg[rl * 65 + o] = g;
  }
  __syncthreads();
  const int nl = tid & 63;
  float4 hv[16];                                // hoist own hg row (64 VGPR)
#pragma unroll
  for (int k = 0; k < 16; ++k) hv[k] = *(const float4*)&hg[nl * 65 + 4 * k];
#pragma unroll
  for (int i = 0; i < 16; ++i) {
    int o2 = q + i * 4;                         // wave-uniform
    float acc = b2[o2];
#pragma unroll
    for (int k = 0; k < 16; ++k) {
      float4 wv = *(const float4*)&wT2[o2 * 65 + 4 * k];  // uniform -> broadcast
      acc += hv[k].x * wv.x; acc += hv[k].y * wv.y;       // ascending oo: same
      acc += hv[k].z * wv.z; acc += hv[k].w * wv.w;       //  order as before
    }
    out[((size_t)(b * 64 + o2)) * N_ + n0 + nl] = acc;    // coalesced over n
  }
}

extern "C" void kernel_launch(void* const* d_in, const int* in_sizes, int n_in,
                              void* d_out, int out_size, void* d_ws, size_t ws_size,
                              hipStream_t stream) {
  const float* x     = (const float*)d_in[0];
  const float* w1    = (const float*)d_in[1];
  const float* b1    = (const float*)d_in[2];
  const float* gamma = (const float*)d_in[3];
  const float* beta  = (const float*)d_in[4];
  const float* w2    = (const float*)d_in[5];
  const float* b2    = (const float*)d_in[6];
  const float* eps_g = (const float*)d_in[7];
  float* out = (float*)d_out;

  char* ws = (char*)d_ws;
  float* xf   = (float*)(ws + OFF_XF);
  float* sq   = (float*)(ws + OFF_SQ);
  u32*   kd   = (u32*)  (ws + OFF_KD);
  u16*   ki   = (u16*)  (ws + OFF_KI);
  u16*   pack = (u16*)  (ws + OFF_PACK);
  float* h1   = (float*)(ws + OFF_H1);         // aliases pack head (dead after knn)
  float* bn_acc = (float*)(ws + OFF_BN);       // own region; zeroed by k_knn blk 0

  k_transpose<<<512, 256, 0, stream>>>(x, xf, sq, pack);
  k_knn<<<1024, 256, 0, stream>>>(pack, sq, kd, ki, bn_acc);
  k_mid<<<ROWS_ / MIDROWS_, 256, 0, stream>>>(kd, ki, xf, eps_g, w1, b1, h1, bn_acc);
  k_final<<<ROWS_ / 64, 256, 0, stream>>>(h1, bn_acc, gamma, beta, w2, b2, out);
}

// Round 13
// 328.585 us; speedup vs baseline: 1.6326x; 1.6326x over previous
//
#include <hip/hip_runtime.h>
#include <cstdint>
#include <cstddef>

#define B_ 8
#define C_ 64
#define N_ 4096
#define O_ 64
#define ROWS_ (B_*N_)          // 32768
#define NSPLIT_ 2              // candidate splits per row in k_knn
#define CAPB_ 33               // per-lane LDS candidate cap (odd u64 stride: 2-way, free)
#define TAU_TILES_ 8           // tiles scanned for the tau upper bound
#define MIDROWS_ 16            // rows per k_mid block (TLP: 2048 blocks)
#define FINROWS_ 32            // rows per k_final block (TLP: 1024 blocks)

typedef unsigned long long u64;
typedef unsigned int u32;
typedef unsigned short u16;
typedef __attribute__((ext_vector_type(8))) short bf16x8;   // 8 bf16 = 4 VGPR
typedef __attribute__((ext_vector_type(16))) float f32x16;  // MFMA 32x32 acc

#define MFMA32(A,Bv,Cv) __builtin_amdgcn_mfma_f32_32x32x16_bf16(A,Bv,Cv,0,0,0)

// ---- workspace layout (bytes), total 35,782,656 ----
// xf   [ROWS][64] f32 : 0           (8 MB)   alive: transpose -> mid
// sq   [ROWS]     f32 : 8388608     (128 KB) alive: transpose -> knn
// kd   [ROWS][2][16] u32 : 8519680  (4 MB)   alive: knn -> mid
// ki   [ROWS][2][16] u16 : 16908288 (2 MB)   alive: knn -> mid
// pack [B][128][12][64][8] bf16 : 21102592 (12 MB) alive: transpose -> knn
// -- aliases (dead regions reused): --
// h1   [ROWS][64] f32 : 21102592 (over pack head, dead after knn; mid -> final)
// bn   acc[128]       : 33685504 (own region; zeroed by k_knn block 0)
#define OFF_XF   0
#define OFF_SQ   8388608
#define OFF_KD   8519680
#define OFF_KI   16908288
#define OFF_PACK 21102592
#define OFF_H1   21102592
#define OFF_BN   33685504

__device__ __forceinline__ void insert16(u64 kv[16], u64 key) {
  if (key < kv[15]) {
#pragma unroll
    for (int j = 15; j > 0; --j) {
      u64 a = kv[j-1], b = kv[j];
      kv[j] = (key < a) ? a : ((key < b) ? key : b);
    }
    kv[0] = (key < kv[0]) ? key : kv[0];
  }
}

// ---------------- K1: transpose [B,C,N] -> xf[B,N,C], sq, and bf16 split-pack ----
// 1024 blocks (4/CU): 32-n tiles; each block emits exactly one pack tile.
__global__ __launch_bounds__(256) void k_transpose(const float* __restrict__ x,
                                                   float* __restrict__ xf,
                                                   float* __restrict__ sq,
                                                   u16* __restrict__ pack) {
  __shared__ float lds[64 * 33];           // 64 c x 32 n, pad 33
  const int b  = blockIdx.x >> 7;          // 8 batches
  const int nt = blockIdx.x & 127;         // 128 n-tiles of 32
  const int n0 = nt << 5;
  const int tid = threadIdx.x;
  const float* xb = x + (size_t)b * C_ * N_;
  {
    const int nn = tid & 31;
    const int c0 = tid >> 5;               // 0..7
#pragma unroll
    for (int i = 0; i < 8; ++i) {
      int c = c0 + i * 8;
      lds[c * 33 + nn] = xb[(size_t)c * N_ + n0 + nn];   // 128B segments over n
    }
  }
  __syncthreads();
  {
    const int cc  = tid & 63;
    const int nn0 = tid >> 6;              // 0..3
#pragma unroll
    for (int i = 0; i < 8; ++i) {
      int nn = nn0 + i * 4;
      xf[((size_t)(b * N_ + n0 + nn)) * 64 + cc] = lds[cc * 33 + nn]; // coalesced over c
    }
  }
  if (tid < 32) {
    float s = 0.f;
#pragma unroll
    for (int c = 0; c < 64; ++c) { float v = lds[c * 33 + tid]; s += v * v; }
    sq[b * N_ + n0 + tid] = s;
  }
  {
    const int lane = tid & 63;
    const int slice = tid >> 6;                  // 4 k-slices of 16
    const int kb = slice * 16 + (lane >> 5) * 8;
    const int nl = lane & 31;
    bf16x8 H, M, L;
#pragma unroll
    for (int j = 0; j < 8; ++j) {
      float f = lds[(kb + j) * 33 + nl];
      u32 u = __float_as_uint(f);
      u32 rh = (u + 0x7FFFu + ((u >> 16) & 1u)) >> 16;   // RNE to bf16
      float bh = __uint_as_float(rh << 16);
      float f1 = f - bh;                                  // exact (Sterbenz)
      u = __float_as_uint(f1);
      u32 rm = (u + 0x7FFFu + ((u >> 16) & 1u)) >> 16;
      float bm = __uint_as_float(rm << 16);
      float f2 = f1 - bm;                                 // exact
      u = __float_as_uint(f2);
      u32 rl = (u + 0x7FFFu + ((u >> 16) & 1u)) >> 16;
      H[j] = (short)rh; M[j] = (short)rm; L[j] = (short)rl;
    }
    u16* basep = pack + ((size_t)(b * 128 + nt) * 12) * 512 + lane * 8;
    *(bf16x8*)(basep + (size_t)(0 + slice) * 512) = H;
    *(bf16x8*)(basep + (size_t)(4 + slice) * 512) = M;
    *(bf16x8*)(basep + (size_t)(8 + slice) * 512) = L;
  }
}

// ---------------- K2: MFMA distances; tau-bound + collect (r7/r11-proven) ----------
#define KNN_LOAD(P, mt) do { const u16* ap_ = pb + (size_t)(mt) * (12*512); \
  P##h0 = *(const bf16x8*)(ap_ + 0*512);  P##h1 = *(const bf16x8*)(ap_ + 1*512); \
  P##h2 = *(const bf16x8*)(ap_ + 2*512);  P##h3 = *(const bf16x8*)(ap_ + 3*512); \
  P##m0 = *(const bf16x8*)(ap_ + 4*512);  P##m1 = *(const bf16x8*)(ap_ + 5*512); \
  P##m2 = *(const bf16x8*)(ap_ + 6*512);  P##m3 = *(const bf16x8*)(ap_ + 7*512); \
  P##l0 = *(const bf16x8*)(ap_ + 8*512);  P##l1 = *(const bf16x8*)(ap_ + 9*512); \
  P##l2 = *(const bf16x8*)(ap_ +10*512);  P##l3 = *(const bf16x8*)(ap_ +11*512); } while(0)

#define SQ_LOAD(MT) do { const float* sp_ = sqb + (MT) * 32 + 4 * h; \
  sv0 = *(const float4*)(sp_);      sv1 = *(const float4*)(sp_ + 8); \
  sv2 = *(const float4*)(sp_ + 16); sv3 = *(const float4*)(sp_ + 24); } while(0)

#define KNN_MFMA(P) \
  acc0 = MFMA32(P##h0, ql0, acc0);  acc1 = MFMA32(P##h1, ql1, acc1); \
  acc0 = MFMA32(P##l0, qh0, acc0);  acc1 = MFMA32(P##l1, qh1, acc1); \
  acc0 = MFMA32(P##m0, qm0, acc0);  acc1 = MFMA32(P##m1, qm1, acc1); \
  acc0 = MFMA32(P##h0, qm0, acc0);  acc1 = MFMA32(P##h1, qm1, acc1); \
  acc0 = MFMA32(P##m0, qh0, acc0);  acc1 = MFMA32(P##m1, qh1, acc1); \
  acc0 = MFMA32(P##h0, qh0, acc0);  acc1 = MFMA32(P##h1, qh1, acc1); \
  acc0 = MFMA32(P##h2, ql2, acc0);  acc1 = MFMA32(P##h3, ql3, acc1); \
  acc0 = MFMA32(P##l2, qh2, acc0);  acc1 = MFMA32(P##l3, qh3, acc1); \
  acc0 = MFMA32(P##m2, qm2, acc0);  acc1 = MFMA32(P##m3, qm3, acc1); \
  acc0 = MFMA32(P##h2, qm2, acc0);  acc1 = MFMA32(P##h3, qm3, acc1); \
  acc0 = MFMA32(P##m2, qh2, acc0);  acc1 = MFMA32(P##m3, qh3, acc1); \
  acc0 = MFMA32(P##h2, qh2, acc0);  acc1 = MFMA32(P##h3, qh3, acc1);

// Loop1 select: direct sorted insert-8 (u32 dist-only keys)
#define SEL_T8() do { \
  float sqv_[16] = {sv0.x, sv0.y, sv0.z, sv0.w, sv1.x, sv1.y, sv1.z, sv1.w, \
                    sv2.x, sv2.y, sv2.z, sv2.w, sv3.x, sv3.y, sv3.z, sv3.w}; \
_Pragma("unroll") \
  for (int r_ = 0; r_ < 16; ++r_) { \
    float d_ = fmaf(-2.f, acc0[r_] + acc1[r_], sqv_[r_]); \
    u32 u_ = __float_as_uint(d_); \
    u_ ^= ((int)u_ < 0) ? 0xFFFFFFFFu : 0x80000000u; \
    if (u_ < kv1[7]) { \
_Pragma("unroll") \
      for (int j_ = 7; j_ > 0; --j_) { \
        u32 a_ = kv1[j_-1], b_ = kv1[j_]; \
        kv1[j_] = (u_ < a_) ? a_ : ((u_ < b_) ? u_ : b_); \
      } \
      kv1[0] = (u_ < kv1[0]) ? u_ : kv1[0]; \
    } \
  } \
} while(0)

// Loop2 select: filtered LDS push (tiny body) + one batched drain vote per tile
#define SEL_C(MT) do { \
  const u32 ic_ = (u32)((MT) * 32 + 4 * h); \
  float sqv_[16] = {sv0.x, sv0.y, sv0.z, sv0.w, sv1.x, sv1.y, sv1.z, sv1.w, \
                    sv2.x, sv2.y, sv2.z, sv2.w, sv3.x, sv3.y, sv3.z, sv3.w}; \
_Pragma("unroll") \
  for (int r_ = 0; r_ < 16; ++r_) { \
    float d_ = fmaf(-2.f, acc0[r_] + acc1[r_], sqv_[r_]); \
    u32 u_ = __float_as_uint(d_); \
    u_ ^= ((int)u_ < 0) ? 0xFFFFFFFFu : 0x80000000u; \
    if (u_ <= tauk) { \
      myc[cnt] = ((u64)u_ << 32) | (u64)(ic_ + (u32)((r_ & 3) + 8 * (r_ >> 2))); \
      ++cnt; \
    } \
  } \
  if (__any(cnt >= CAPB_ - 16)) {            /* capacity: <=16 adds/tile, cap 33 */ \
    for (int i_ = 0; i_ < cnt; ++i_) insert16(kv, myc[i_]); \
    cnt = 0; \
  } \
} while(0)

__global__ __launch_bounds__(256, 2) void k_knn(const u16* __restrict__ pack,
                                                const float* __restrict__ sq,
                                                u32* __restrict__ kd,
                                                u16* __restrict__ ki,
                                                float* __restrict__ bn_acc) {
  __shared__ u64 cand[256 * CAPB_];          // 67.6 KB: per-lane candidate lists
  const int bx = blockIdx.x;
  const int tid = threadIdx.x;
  if (bx == 0 && tid < 128) bn_acc[tid] = 0.f;   // OFF_BN region untouched elsewhere
  const int split = bx & 1;
  const int qb = (bx >> 1) & 31;
  const int b = bx >> 6;
  const int lane = tid & 63;
  const int wid = tid >> 6;
  const int qt = qb * 4 + wid;               // query tile 0..127
  const int h = lane >> 5;
  const u16* pb = pack + (size_t)b * (128 * 12 * 512) + lane * 8;

  const u16* qp = pb + (size_t)qt * (12 * 512);
  bf16x8 qh0 = *(const bf16x8*)(qp + 0*512), qh1 = *(const bf16x8*)(qp + 1*512);
  bf16x8 qh2 = *(const bf16x8*)(qp + 2*512), qh3 = *(const bf16x8*)(qp + 3*512);
  bf16x8 qm0 = *(const bf16x8*)(qp + 4*512), qm1 = *(const bf16x8*)(qp + 5*512);
  bf16x8 qm2 = *(const bf16x8*)(qp + 6*512), qm3 = *(const bf16x8*)(qp + 7*512);
  bf16x8 ql0 = *(const bf16x8*)(qp + 8*512), ql1 = *(const bf16x8*)(qp + 9*512);
  bf16x8 ql2 = *(const bf16x8*)(qp + 10*512), ql3 = *(const bf16x8*)(qp + 11*512);

  const float* sqb = sq + b * N_;
  const int mbase = split * 64;

  bf16x8 Ah0, Ah1, Ah2, Ah3, Am0, Am1, Am2, Am3, Al0, Al1, Al2, Al3;
  bf16x8 Bh0, Bh1, Bh2, Bh3, Bm0, Bm1, Bm2, Bm3, Bl0, Bl1, Bl2, Bl3;
  float4 sv0, sv1, sv2, sv3;

  // ================= LOOP 1: tau bound from 8 tiles (top-8/lane, u32) ===========
  u32 kv1[8];
#pragma unroll
  for (int j = 0; j < 8; ++j) kv1[j] = 0xFF800000u;    // flip(+INF) sentinel

  KNN_LOAD(A, mbase);
  for (int ct = 0; ct < TAU_TILES_; ct += 2) {
    SQ_LOAD(mbase + ct);
    KNN_LOAD(B, mbase + ct + 1);
    {
      f32x16 acc0 = {0,0,0,0,0,0,0,0,0,0,0,0,0,0,0,0};
      f32x16 acc1 = {0,0,0,0,0,0,0,0,0,0,0,0,0,0,0,0};
      KNN_MFMA(A)
      SEL_T8();
    }
    SQ_LOAD(mbase + ct + 1);
    KNN_LOAD(A, mbase + ct + 2);                       // tile 8 prefetch: valid mem
    {
      f32x16 acc0 = {0,0,0,0,0,0,0,0,0,0,0,0,0,0,0,0};
      f32x16 acc1 = {0,0,0,0,0,0,0,0,0,0,0,0,0,0,0,0};
      KNN_MFMA(B)
      SEL_T8();
    }
  }
  u32 tk = kv1[7];
  u32 pk = (u32)__shfl_xor((int)tk, 32);
  const u32 tauk = (tk > pk) ? tk : pk;    // >= exact 16th-smallest key of the split

  // ================= LOOP 2: collect key <= tau over all 64 tiles ===============
  u64 kv[16];
#pragma unroll
  for (int j = 0; j < 16; ++j) kv[j] = 0xFF8000000000FFFFull;
  int cnt = 0;
  u64* myc = cand + tid * CAPB_;

  KNN_LOAD(A, mbase);
  for (int ct = 0; ct < 64; ct += 2) {
    SQ_LOAD(mbase + ct);
    KNN_LOAD(B, mbase + ct + 1);
    {
      f32x16 acc0 = {0,0,0,0,0,0,0,0,0,0,0,0,0,0,0,0};
      f32x16 acc1 = {0,0,0,0,0,0,0,0,0,0,0,0,0,0,0,0};
      KNN_MFMA(A)
      SEL_C(mbase + ct);
    }
    SQ_LOAD(mbase + ct + 1);
    KNN_LOAD(A, mbase + ((ct + 2) & 63));
    {
      f32x16 acc0 = {0,0,0,0,0,0,0,0,0,0,0,0,0,0,0,0};
      f32x16 acc1 = {0,0,0,0,0,0,0,0,0,0,0,0,0,0,0,0};
      KNN_MFMA(B)
      SEL_C(mbase + ct + 1);
    }
  }
  for (int i = 0; i < cnt; ++i) insert16(kv, myc[i]);  // final drain

  // merge lane halves (half-cleaner -> bitonic), then bitonic-merge sort
  u64 m[16];
#pragma unroll
  for (int j = 0; j < 16; ++j) {
    u64 p = __shfl_xor(kv[15 - j], 32);
    m[j] = (kv[j] < p) ? kv[j] : p;
  }
#pragma unroll
  for (int d = 8; d >= 1; d >>= 1) {
#pragma unroll
    for (int j = 0; j < 16; ++j) {
      if ((j & d) == 0) {
        u64 a = m[j], c = m[j | d];
        m[j] = (a < c) ? a : c;
        m[j | d] = (a < c) ? c : a;
      }
    }
  }

  if (lane < 32) {
    const int row = b * N_ + qt * 32 + lane;
    u32* dp = kd + ((size_t)row * NSPLIT_ + split) * 16;
    u16* ip = ki + ((size_t)row * NSPLIT_ + split) * 16;
#pragma unroll
    for (int j = 0; j < 16; ++j) {
      dp[j] = (u32)(m[j] >> 32);
      ip[j] = (u16)(m[j] & 0xFFFFu);
    }
  }
}

// ---------------- K3: fused merge + GIN aggregation + GEMM1 + BN partial sums ----
__global__ __launch_bounds__(256) void k_mid(const u32* __restrict__ kd,
                                             const u16* __restrict__ ki,
                                             const float* __restrict__ xf,
                                             const float* __restrict__ eps_gin,
                                             const float* __restrict__ w1,
                                             const float* __restrict__ b1,
                                             float* __restrict__ h1,
                                             float* __restrict__ bn_acc) {
  __shared__ float wT[64 * 65];                 // w1 transposed: wT[o][c] (16.6 KB)
  __shared__ float hL[MIDROWS_ * 65];           // aggregated rows (4.2 KB)
  __shared__ int   knnL[MIDROWS_ * 16];
  __shared__ float rs[4][64], rs2[4][64];
  const int tid = threadIdx.x;
  const int r0 = blockIdx.x * MIDROWS_;
#pragma unroll
  for (int i = 0; i < 16; ++i) {
    int idx = tid + i * 256;                    // w1[c][o], idx = c*64+o
    wT[(idx & 63) * 65 + (idx >> 6)] = w1[idx];
  }
  {
    const int row = tid >> 4;                   // 16 rows x 16 j = 256 threads
    const int j = tid & 15;
    const u32* dp = kd + (size_t)(r0 + row) * (NSPLIT_ * 16);
    const u16* ip = ki + (size_t)(r0 + row) * (NSPLIT_ * 16);
    u64 a = ((u64)dp[j] << 32) | ip[j];
    u64 bb = ((u64)dp[16 + (15 - j)] << 32) | ip[16 + (15 - j)];
    knnL[row * 16 + j] = (int)((a < bb ? a : bb) & 0xFFFFu);  // set semantics
  }
  __syncthreads();
  const int c = tid & 63;
  const int q = tid >> 6;
  const int b = r0 >> 12;
  const float* xfb = xf + (size_t)b * N_ * 64;
  const float eps1 = 1.f + eps_gin[0];
#pragma unroll
  for (int i = 0; i < 4; ++i) {
    int rl = q * 4 + i;                         // wave-uniform row
    float v = eps1 * xfb[(size_t)((r0 & (N_ - 1)) + rl) * 64 + c];
    const int* kn = knnL + rl * 16;
#pragma unroll
    for (int j = 0; j < 16; ++j) {
      int mr = kn[j];                           // wave-uniform LDS broadcast
      v += xfb[(size_t)mr * 64 + c];            // coalesced 256B row read
    }
    hL[rl * 65 + c] = v;
  }
  __syncthreads();
  const int o = c;
  const float bias = b1[o];
  float s = 0.f, s2 = 0.f;
#pragma unroll
  for (int i = 0; i < 4; ++i) {
    int rl = q * 4 + i;
    float acc = bias;
#pragma unroll
    for (int k = 0; k < 16; ++k) {
      float4 hv = *(const float4*)&hL[rl * 65 + 4 * k];   // uniform -> broadcast
      float4 wv = *(const float4*)&wT[o * 65 + 4 * k];    // pad-65: conflict-free
      acc += hv.x * wv.x; acc += hv.y * wv.y;             // ascending c: same order
      acc += hv.z * wv.z; acc += hv.w * wv.w;             //  as previous kernel
    }
    h1[(size_t)(r0 + rl) * 64 + o] = acc;
    s += acc; s2 += acc * acc;
  }
  rs[q][o] = s; rs2[q][o] = s2;
  __syncthreads();
  if (tid < 64) {
    float ts  = rs[0][tid] + rs[1][tid] + rs[2][tid] + rs[3][tid];
    float ts2 = rs2[0][tid] + rs2[1][tid] + rs2[2][tid] + rs2[3][tid];
    atomicAdd(&bn_acc[tid], ts);
    atomicAdd(&bn_acc[64 + tid], ts2);
  }
}

// ---------------- K4: BN finalize + apply + GELU(erf) + GEMM2 + transposed store ----
// 1024 blocks of 32 rows (TLP: ~6 blocks/CU by LDS). Same ascending-oo dot order.
__global__ __launch_bounds__(256) void k_final(const float* __restrict__ h1,
                                               const float* __restrict__ bn_acc,
                                               const float* __restrict__ gamma,
                                               const float* __restrict__ beta,
                                               const float* __restrict__ w2,
                                               const float* __restrict__ b2,
                                               float* __restrict__ out) {
  __shared__ float wT2[64 * 65];                // w2 transposed: wT2[o2][oo] (16.6 KB)
  __shared__ float hg[FINROWS_ * 65];           // 8.3 KB, padded
  __shared__ float scsh[128];
  const int tid = threadIdx.x;
#pragma unroll
  for (int i = 0; i < 16; ++i) {
    int idx = tid + i * 256;                    // w2[oo][o2], idx = oo*64+o2
    wT2[(idx & 63) * 65 + (idx >> 6)] = w2[idx];
  }
  if (tid < 64) {                               // fused BN finalize (per-block recompute)
    const float inv = 1.f / (float)ROWS_;
    float mean = bn_acc[tid] * inv;
    float var  = bn_acc[64 + tid] * inv - mean * mean;
    float sc = gamma[tid] * rsqrtf(var + 1e-5f);
    scsh[tid] = sc;
    scsh[64 + tid] = beta[tid] - mean * sc;
  }
  __syncthreads();
  const int r0 = blockIdx.x * FINROWS_;
  const int b  = r0 >> 12;
  const int n0 = r0 & (N_ - 1);
  const int o = tid & 63;
  const int q = tid >> 6;
  const float sc = scsh[o], sh = scsh[64 + o];
#pragma unroll
  for (int i = 0; i < 8; ++i) {
    int rl = q + i * 4;                         // rows 0..31
    float v = h1[(size_t)(r0 + rl) * 64 + o] * sc + sh;
    float g = 0.5f * v * (1.f + erff(v * 0.70710678118654752f));
    hg[rl * 65 + o] = g;
  }
  __syncthreads();
  const int nl = tid & 31;
  const int g8 = tid >> 5;                      // 8 o2-groups
  float4 hv[16];                                // hoist own hg row (64 VGPR)
#pragma unroll
  for (int k = 0; k < 16; ++k) hv[k] = *(const float4*)&hg[nl * 65 + 4 * k];
#pragma unroll
  for (int i = 0; i < 8; ++i) {
    int o2 = g8 * 8 + i;                        // half-wave-uniform
    float acc = b2[o2];
#pragma unroll
    for (int k = 0; k < 16; ++k) {
      float4 wv = *(const float4*)&wT2[o2 * 65 + 4 * k];  // broadcast per half-wave
      acc += hv[k].x * wv.x; acc += hv[k].y * wv.y;       // ascending oo: same
      acc += hv[k].z * wv.z; acc += hv[k].w * wv.w;       //  order as before
    }
    out[((size_t)(b * 64 + o2)) * N_ + n0 + nl] = acc;    // 128B segments over n
  }
}

extern "C" void kernel_launch(void* const* d_in, const int* in_sizes, int n_in,
                              void* d_out, int out_size, void* d_ws, size_t ws_size,
                              hipStream_t stream) {
  const float* x     = (const float*)d_in[0];
  const float* w1    = (const float*)d_in[1];
  const float* b1    = (const float*)d_in[2];
  const float* gamma = (const float*)d_in[3];
  const float* beta  = (const float*)d_in[4];
  const float* w2    = (const float*)d_in[5];
  const float* b2    = (const float*)d_in[6];
  const float* eps_g = (const float*)d_in[7];
  float* out = (float*)d_out;

  char* ws = (char*)d_ws;
  float* xf   = (float*)(ws + OFF_XF);
  float* sq   = (float*)(ws + OFF_SQ);
  u32*   kd   = (u32*)  (ws + OFF_KD);
  u16*   ki   = (u16*)  (ws + OFF_KI);
  u16*   pack = (u16*)  (ws + OFF_PACK);
  float* h1   = (float*)(ws + OFF_H1);         // aliases pack head (dead after knn)
  float* bn_acc = (float*)(ws + OFF_BN);       // own region; zeroed by k_knn blk 0

  k_transpose<<<1024, 256, 0, stream>>>(x, xf, sq, pack);
  k_knn<<<512, 256, 0, stream>>>(pack, sq, kd, ki, bn_acc);
  k_mid<<<ROWS_ / MIDROWS_, 256, 0, stream>>>(kd, ki, xf, eps_g, w1, b1, h1, bn_acc);
  k_final<<<ROWS_ / FINROWS_, 256, 0, stream>>>(h1, bn_acc, gamma, beta, w2, b2, out);
}